// Round 5
// baseline (79.573 us; speedup 1.0000x reference)
//
#include <hip/hip_runtime.h>

#define B_TOTAL 262144
#define K_CB    512
#define D_DIM   3
#define BLOCK   256
#define LUT_N   2048              // buckets over [-4, 4), width 1/256
#define LUT_E   (LUT_N + 1)       // 2049 edge counts
#define LUT_PAD 2052              // per-dim stride (uint-aligned)

// monotone map fp32 bits -> uint32 (ascending float => ascending uint)
__device__ __forceinline__ unsigned int mono32(unsigned int u) {
    unsigned int m = (u & 0x80000000u) ? 0xFFFFFFFFu : 0x80000000u;
    return u ^ m;
}

// ---------------- kernel 1: rank-sort codebook + build prefix-count LUT ------
// 3 blocks (one per dim). ws: ws_val[3][512] | ws_idx[3][512] | ws_lut[3][2052]
__global__ __launch_bounds__(BLOCK) void rank_lut_kernel(
    const float* __restrict__ e, float* __restrict__ ws_val,
    int* __restrict__ ws_idx, unsigned short* __restrict__ ws_lut)
{
    const int d   = blockIdx.x;
    const int tid = threadIdx.x;

    __shared__ unsigned long long key[K_CB];
    __shared__ float vals[K_CB];
    __shared__ float sval[K_CB];
    __shared__ int   sidx[K_CB];

    for (int k = tid; k < K_CB; k += BLOCK) {
        float v = e[k * D_DIM + d];
        vals[k] = v;
        key[k]  = ((unsigned long long)mono32(__float_as_uint(v)) << 32)
                | (unsigned int)k;
    }
    __syncthreads();

    // rank by counting: lexicographic (value, orig idx) => stable sort order
    const unsigned long long my0 = key[tid], my1 = key[tid + BLOCK];
    int r0 = 0, r1 = 0;
    #pragma unroll 8
    for (int j = 0; j < K_CB; ++j) {
        unsigned long long kj = key[j];       // wave-uniform: LDS broadcast
        r0 += (kj < my0) ? 1 : 0;
        r1 += (kj < my1) ? 1 : 0;
    }
    sval[r0] = vals[tid];         sidx[r0] = tid;
    sval[r1] = vals[tid + BLOCK]; sidx[r1] = tid + BLOCK;
    __syncthreads();

    for (int k = tid; k < K_CB; k += BLOCK) {
        ws_val[d * K_CB + k] = sval[k];
        ws_idx[d * K_CB + k] = sidx[k];
    }

    // LUT: lut[t] = count(val <= e_t), e_t = -4 + t/256 (exact in fp32)
    for (int t = tid; t < LUT_E; t += BLOCK) {
        float edge = -4.0f + (float)t * 0.00390625f;
        int lo = 0, hi = K_CB;                // first index with val > edge
        while (lo < hi) { int mid = (lo + hi) >> 1;
                          if (sval[mid] <= edge) lo = mid + 1; else hi = mid; }
        ws_lut[d * LUT_PAD + t] = (unsigned short)lo;
    }
}

// ---------------- kernel 2: LUT-bracketed nearest search ---------------------
__global__ __launch_bounds__(BLOCK) void vq_search_kernel(
    const float* __restrict__ ze,
    const float* __restrict__ ws_val, const int* __restrict__ ws_idx,
    const unsigned int* __restrict__ ws_lut_u32,
    float* __restrict__ z_out, float* __restrict__ zq_out)
{
    __shared__ float          sval[D_DIM][K_CB];    // 6 KB
    __shared__ int            sidx[D_DIM][K_CB];    // 6 KB
    __shared__ unsigned short slut[D_DIM][LUT_PAD]; // 12.3 KB

    const int tid = threadIdx.x;
    { // staged, vectorized
        const float4* gv = (const float4*)ws_val; float4* lv = (float4*)sval;
        for (int i = tid; i < D_DIM * K_CB / 4; i += BLOCK) lv[i] = gv[i];
        const int4* gi = (const int4*)ws_idx; int4* li = (int4*)sidx;
        for (int i = tid; i < D_DIM * K_CB / 4; i += BLOCK) li[i] = gi[i];
        unsigned int* ll = (unsigned int*)slut;
        for (int i = tid; i < D_DIM * LUT_PAD / 2; i += BLOCK) ll[i] = ws_lut_u32[i];
    }
    __syncthreads();

    const int b = blockIdx.x * BLOCK + tid;
    const float xs[D_DIM] = { ze[b * 3 + 0], ze[b * 3 + 1], ze[b * 3 + 2] };

    #pragma unroll
    for (int d = 0; d < D_DIM; ++d) {
        const float xv = xs[d];

        // bucket of xv; clamp the float before int-cast (guards inf/huge)
        float tf = floorf((xv + 4.0f) * 256.0f);
        int t = (int)fmaxf(fminf(tf, 1.0e6f), -1.0e6f);

        // widened bracket (provably safe: bucket-index rounding err << width):
        // lo: sval[lo] <= xv, hi: sval[hi] > xv (virtual sentinels -1 / 512)
        int tl = t - 1;
        int lo = (tl < 0) ? -1
               : (int)slut[d][tl > LUT_N ? LUT_N : tl] - 1;
        int hi = (t >= LUT_N - 2) ? K_CB : (int)slut[d][t + 2];

        while (hi - lo > 1) {                  // typically 0-2 iterations
            int mid = (lo + hi) >> 1;
            bool le = sval[d][mid] <= xv;
            lo = le ? mid : lo;
            hi = le ? hi : mid;
        }

        // left candidate: walk to head of equal-value run (min orig idx)
        float dl = 3.402823466e38f, vl = 0.0f; int il = 0;
        if (lo >= 0) {
            vl = sval[d][lo];
            int p = lo;
            while (p > 0 && sval[d][p - 1] == vl) --p;
            il = sidx[d][p];
            float tt = xv - vl;                // identical fp32 arith to ref
            dl = tt * tt;
        }
        // right candidate (group head by (value,idx)-sort construction)
        float dr = 3.402823466e38f, vr = 0.0f; int ir = 0;
        if (lo < K_CB - 1) {
            vr = sval[d][lo + 1];
            ir = sidx[d][lo + 1];
            float tt = xv - vr;
            dr = tt * tt;
        }

        // np.argmin semantics: strict min; tie -> smaller original index
        const bool pickR = (dr < dl) || ((dr == dl) && (ir < il));
        z_out [b * 3 + d] = (float)(pickR ? ir : il);
        zq_out[b * 3 + d] = pickR ? vr : vl;
    }
}

extern "C" void kernel_launch(void* const* d_in, const int* in_sizes, int n_in,
                              void* d_out, int out_size, void* d_ws, size_t ws_size,
                              hipStream_t stream) {
    const float* ze = (const float*)d_in[0];
    const float* e  = (const float*)d_in[1];
    float* z_out  = (float*)d_out;                    // z  : B*D float32
    float* zq_out = z_out + (size_t)B_TOTAL * D_DIM;  // zq : B*D float32

    float*          ws_val = (float*)d_ws;                        // [3][512]
    int*            ws_idx = (int*)(ws_val + D_DIM * K_CB);       // [3][512]
    unsigned short* ws_lut = (unsigned short*)(ws_idx + D_DIM * K_CB); // [3][2052]

    rank_lut_kernel <<<D_DIM,           BLOCK, 0, stream>>>(e, ws_val, ws_idx, ws_lut);
    vq_search_kernel<<<B_TOTAL / BLOCK, BLOCK, 0, stream>>>(ze, ws_val, ws_idx,
                                                            (const unsigned int*)ws_lut,
                                                            z_out, zq_out);
}